// Round 1
// baseline (80.330 us; speedup 1.0000x reference)
//
#include <hip/hip_runtime.h>

// DualPathFusion: B=2, C=32, D=32, H=128, W=128, f32.
// out[b,c,s] = f1*wg1 + f2*wg2 where wg = softmax over 2 logits that are
// per-channel linear combos of f1, f2 (avg term folded into coefficients).
// Single pass: hold all 32 channels of f1,f2 per spatial position in regs.

#define CCH 32
#define LOG2_SPATIAL 19          // D*H*W = 32*128*128 = 2^19
#define SPATIAL (1u << LOG2_SPATIAL)

__global__ __launch_bounds__(256) void dual_path_fusion_kernel(
    const float* __restrict__ f1, const float* __restrict__ f2,
    const float* __restrict__ w1, const float* __restrict__ b1,
    const float* __restrict__ w2, const float* __restrict__ b2,
    float* __restrict__ out, unsigned total)
{
    unsigned s = blockIdx.x * blockDim.x + threadIdx.x;
    if (s >= total) return;                 // total = B * SPATIAL (exact multiple anyway)
    unsigned bb = s >> LOG2_SPATIAL;        // batch index
    unsigned r  = s & (SPATIAL - 1u);       // spatial offset within batch
    unsigned base = (bb << (LOG2_SPATIAL + 5)) + r;   // b*C*SPATIAL + r

    // Load all channels of both features into registers (coalesced dword loads).
    float x1[CCH], x2[CCH];
#pragma unroll
    for (int c = 0; c < CCH; ++c) {
        x1[c] = f1[base + ((unsigned)c << LOG2_SPATIAL)];
        x2[c] = f2[base + ((unsigned)c << LOG2_SPATIAL)];
    }

    // Logits with the avg-term folded in:
    //   a1 = sum f1*(w1[c] + .5*w1[C+c]) + f2*(.5*w1[C+c]) + b1
    //   a2 = sum f2*(w2[c] + .5*w2[C+c]) + f1*(.5*w2[C+c]) + b2
    float a1 = b1[0];
    float a2 = b2[0];
#pragma unroll
    for (int c = 0; c < CCH; ++c) {
        float h1 = 0.5f * w1[CCH + c];      // uniform (scalar) loads
        float h2 = 0.5f * w2[CCH + c];
        a1 = fmaf(x1[c], w1[c] + h1, fmaf(x2[c], h1, a1));
        a2 = fmaf(x2[c], w2[c] + h2, fmaf(x1[c], h2, a2));
    }

    // 2-way softmax
    float e   = __expf(a2 - a1);
    float wg1 = 1.0f / (1.0f + e);
    float wg2 = 1.0f - wg1;

#pragma unroll
    for (int c = 0; c < CCH; ++c) {
        out[base + ((unsigned)c << LOG2_SPATIAL)] = fmaf(x1[c], wg1, x2[c] * wg2);
    }
}

extern "C" void kernel_launch(void* const* d_in, const int* in_sizes, int n_in,
                              void* d_out, int out_size, void* d_ws, size_t ws_size,
                              hipStream_t stream) {
    const float* f1 = (const float*)d_in[0];
    const float* f2 = (const float*)d_in[1];
    const float* w1 = (const float*)d_in[2];
    const float* b1 = (const float*)d_in[3];
    const float* w2 = (const float*)d_in[4];
    const float* b2 = (const float*)d_in[5];
    float* out = (float*)d_out;

    unsigned total = (unsigned)(in_sizes[0] / CCH);   // B * D * H * W = 1,048,576
    unsigned block = 256;
    unsigned grid  = (total + block - 1) / block;     // 4096
    dual_path_fusion_kernel<<<grid, block, 0, stream>>>(f1, f2, w1, b1, w2, b2, out, total);
}

// Round 3
// 66.426 us; speedup vs baseline: 1.2093x; 1.2093x over previous
//
#include <hip/hip_runtime.h>

// DualPathFusion: B=2, C=32, D=32, H=128, W=128, f32.
// out[b,c,s] = f1*wg1 + f2*wg2, wg = 2-way softmax of per-channel linear
// combos of (f1, avg) and (f2, avg); avg term folded into coefficients.
// Single pass; 2 spatial positions per thread via 8B/lane vector loads,
// non-temporal stores so the output doesn't evict f1/f2 from L3 between
// graph replays. Uses clang ext_vector float2 (HIP_vector_type is a struct
// and is rejected by __builtin_nontemporal_store).

#define CCH 32
#define LOG2_SPATIAL 19          // D*H*W = 32*128*128 = 2^19
#define SPATIAL (1u << LOG2_SPATIAL)

typedef float f32x2 __attribute__((ext_vector_type(2)));

__global__ __launch_bounds__(256) void dual_path_fusion_kernel(
    const float* __restrict__ f1, const float* __restrict__ f2,
    const float* __restrict__ w1, const float* __restrict__ b1,
    const float* __restrict__ w2, const float* __restrict__ b2,
    float* __restrict__ out, unsigned npairs)
{
    unsigned t = blockIdx.x * blockDim.x + threadIdx.x;
    if (t >= npairs) return;
    unsigned p  = t << 1;                    // first of 2 consecutive positions
    unsigned bb = p >> LOG2_SPATIAL;         // batch index (pairs never straddle)
    unsigned r  = p & (SPATIAL - 1u);
    unsigned base = (bb << (LOG2_SPATIAL + 5)) + r;   // b*C*SPATIAL + r

    // Load all channels of both features for both positions (8B/lane).
    f32x2 x1[CCH], x2[CCH];
#pragma unroll
    for (int c = 0; c < CCH; ++c) {
        x1[c] = *(const f32x2*)(f1 + base + ((unsigned)c << LOG2_SPATIAL));
        x2[c] = *(const f32x2*)(f2 + base + ((unsigned)c << LOG2_SPATIAL));
    }

    // Logits with the avg-term folded in (w loads are wave-uniform -> SALU):
    //   a1 = sum f1*(w1[c] + .5*w1[C+c]) + f2*(.5*w1[C+c]) + b1
    //   a2 = sum f2*(w2[c] + .5*w2[C+c]) + f1*(.5*w2[C+c]) + b2
    float a1x = b1[0], a1y = b1[0];
    float a2x = b2[0], a2y = b2[0];
#pragma unroll
    for (int c = 0; c < CCH; ++c) {
        float h1 = 0.5f * w1[CCH + c];
        float h2 = 0.5f * w2[CCH + c];
        float c1 = w1[c] + h1;
        float c2 = w2[c] + h2;
        a1x = fmaf(x1[c].x, c1, fmaf(x2[c].x, h1, a1x));
        a1y = fmaf(x1[c].y, c1, fmaf(x2[c].y, h1, a1y));
        a2x = fmaf(x2[c].x, c2, fmaf(x1[c].x, h2, a2x));
        a2y = fmaf(x2[c].y, c2, fmaf(x1[c].y, h2, a2y));
    }

    // 2-way softmax per position
    float ex  = __expf(a2x - a1x);
    float ey  = __expf(a2y - a1y);
    float g1x = 1.0f / (1.0f + ex), g2x = 1.0f - g1x;
    float g1y = 1.0f / (1.0f + ey), g2y = 1.0f - g1y;

#pragma unroll
    for (int c = 0; c < CCH; ++c) {
        f32x2 o;
        o.x = fmaf(x1[c].x, g1x, x2[c].x * g2x);
        o.y = fmaf(x1[c].y, g1y, x2[c].y * g2y);
        __builtin_nontemporal_store(o, (f32x2*)(out + base + ((unsigned)c << LOG2_SPATIAL)));
    }
}

extern "C" void kernel_launch(void* const* d_in, const int* in_sizes, int n_in,
                              void* d_out, int out_size, void* d_ws, size_t ws_size,
                              hipStream_t stream) {
    const float* f1 = (const float*)d_in[0];
    const float* f2 = (const float*)d_in[1];
    const float* w1 = (const float*)d_in[2];
    const float* b1 = (const float*)d_in[3];
    const float* w2 = (const float*)d_in[4];
    const float* b2 = (const float*)d_in[5];
    float* out = (float*)d_out;

    unsigned total  = (unsigned)(in_sizes[0] / CCH);  // B*D*H*W = 1,048,576 positions
    unsigned npairs = total >> 1;                     // 524,288 threads
    unsigned block  = 256;
    unsigned grid   = (npairs + block - 1) / block;   // 2048
    dual_path_fusion_kernel<<<grid, block, 0, stream>>>(f1, f2, w1, b1, w2, b2, out, npairs);
}